// Round 5
// baseline (310.277 us; speedup 1.0000x reference)
//
#include <hip/hip_runtime.h>
#include <hip/hip_bf16.h>

#define NB   32
#define CH   64
#define LL   2048
#define OUTC 128

typedef float  f32x4  __attribute__((ext_vector_type(4)));
typedef short  s16x8  __attribute__((ext_vector_type(8)));
typedef unsigned short u16;

__device__ __forceinline__ u16 f2bf(float f) {
  unsigned int u = __builtin_bit_cast(unsigned int, f);
  u += 0x7FFFu + ((u >> 16) & 1u);           // RNE (scalar epilogue use)
  return (u16)(u >> 16);
}

// 8x fp32 -> 8x bf16 via v_cvt_pk_bf16_f32 (compiler-emitted, RNE)
__device__ __forceinline__ s16x8 pack8c(const float* v) {
  s16x8 r;
#pragma unroll
  for (int j = 0; j < 8; j += 2) {
    __hip_bfloat162 h = __float22bfloat162_rn(make_float2(v[j], v[j + 1]));
    short2 s;
    __builtin_memcpy(&s, &h, sizeof(s));
    r[j] = s.x; r[j + 1] = s.y;
  }
  return r;
}

// ---------------------------------------------------------------------------
// K0: x (fp32->bf16), W (fp32->bf16)
// ---------------------------------------------------------------------------
#define NX (NB * CH * LL)          // 4,194,304
#define NW (OUTC * 3 * CH)         // 24,576
__global__ __launch_bounds__(256)
void cvt_inputs(const float* __restrict__ x, const float* __restrict__ W,
                u16* __restrict__ xb, u16* __restrict__ Wb)
{
  const size_t t8 = ((size_t)blockIdx.x * 256 + threadIdx.x) * 8;
  if (t8 < NX) {
    float v[8];
    *(f32x4*)(v)     = *(const f32x4*)(x + t8);
    *(f32x4*)(v + 4) = *(const f32x4*)(x + t8 + 4);
    *(s16x8*)(xb + t8) = pack8c(v);
  } else if (t8 - NX < NW) {
    const size_t w8 = t8 - NX;
    float v[8];
    *(f32x4*)(v)     = *(const f32x4*)(W + w8);
    *(f32x4*)(v + 4) = *(const f32x4*)(W + w8 + 4);
    *(s16x8*)(Wb + w8) = pack8c(v);
  }
}

// ---------------------------------------------------------------------------
// K1: y1[n] = xb[n] * m[n]  (+ writes mP bf16 B-fragments for K2)
// 4-buffer, prefetch-distance-2 register pipeline; cvt via v_cvt_pk_bf16_f32.
// ---------------------------------------------------------------------------
__global__ __launch_bounds__(256, 2)
void prop1_pack(const u16* __restrict__ xb, const float* __restrict__ m,
                u16* __restrict__ y1, u16* __restrict__ mP)
{
  const int n    = blockIdx.x >> 4;
  const int lt   = blockIdx.x & 15;
  const int tid  = threadIdx.x;
  const int wave = tid >> 6;
  const int lane = tid & 63;
  const int l15  = lane & 15;
  const int g4   = lane >> 4;
  const int colb = lt * 128 + wave * 32;

  const float* mp = m  + (size_t)n * LL * LL + (size_t)(g4 * 8) * LL + colb + l15;
  const u16*   ap = xb + (size_t)n * CH * LL + (size_t)l15 * LL + g4 * 8;
  u16* q0 = mP + (((size_t)n * 64 * LL + colb + l15) * 4 + g4) * 8; // + kb*65536, h*512
  u16* o  = y1 + (size_t)n * CH * LL + colb + l15;

  f32x4 acc[4][2];
#pragma unroll
  for (int f = 0; f < 4; ++f)
#pragma unroll
    for (int h = 0; h < 2; ++h)
#pragma unroll
      for (int r = 0; r < 4; ++r) acc[f][h][r] = 0.f;

  float bv0[4][8], bv1[4][8];   // [stage][j]
  s16x8 av[4][4];               // [stage][f]

#define K1_LOAD(S, KB)                                                       \
  {                                                                          \
    const float* _mp = mp + (size_t)(KB) * 32 * LL;                          \
    _Pragma("unroll") for (int j = 0; j < 8; ++j) {                          \
      bv0[S][j] = _mp[(size_t)j * LL];                                       \
      bv1[S][j] = _mp[(size_t)j * LL + 16];                                  \
    }                                                                        \
    const u16* _ap = ap + (KB) * 32;                                         \
    _Pragma("unroll") for (int f = 0; f < 4; ++f)                            \
      av[S][f] = *(const s16x8*)(_ap + (size_t)(f * 16) * LL);               \
  }

#define K1_COMP(S, KB)                                                       \
  {                                                                          \
    s16x8 _b0 = pack8c(bv0[S]), _b1 = pack8c(bv1[S]);                        \
    u16* _q = q0 + (size_t)(KB) * 65536;                                     \
    *(s16x8*)(_q)       = _b0;                                               \
    *(s16x8*)(_q + 512) = _b1;                                               \
    _Pragma("unroll") for (int f = 0; f < 4; ++f) {                          \
      acc[f][0] = __builtin_amdgcn_mfma_f32_16x16x32_bf16(av[S][f], _b0, acc[f][0], 0, 0, 0); \
      acc[f][1] = __builtin_amdgcn_mfma_f32_16x16x32_bf16(av[S][f], _b1, acc[f][1], 0, 0, 0); \
    }                                                                        \
  }

  K1_LOAD(0, 0)
  K1_LOAD(1, 1)
  // steady state: iteration at kb computes kb..kb+3, prefetches kb+2..kb+5.
  // Last iteration kb=56 computes 56..59, loads S0<-60, S1<-61.
#pragma unroll 1
  for (int kb = 0; kb < 60; kb += 4) {
    K1_LOAD(2, kb + 2)  K1_COMP(0, kb)
    K1_LOAD(3, kb + 3)  K1_COMP(1, kb + 1)
    K1_LOAD(0, kb + 4)  K1_COMP(2, kb + 2)
    K1_LOAD(1, kb + 5)  K1_COMP(3, kb + 3)
  }
  // tail: S0 holds 60, S1 holds 61
  K1_LOAD(2, 62)  K1_COMP(0, 60)
  K1_LOAD(3, 63)  K1_COMP(1, 61)
  K1_COMP(2, 62)
  K1_COMP(3, 63)

#pragma unroll
  for (int f = 0; f < 4; ++f)
#pragma unroll
    for (int r = 0; r < 4; ++r) {
      const int row = f * 16 + g4 * 4 + r;
      o[(size_t)row * LL]      = f2bf(acc[f][0][r]);
      o[(size_t)row * LL + 16] = f2bf(acc[f][1][r]);
    }
}

// ---------------------------------------------------------------------------
// K2: y2[n] = y1[n] * m[n], reading mP (pre-packed bf16 fragments).
// ---------------------------------------------------------------------------
__global__ __launch_bounds__(256, 2)
void prop2(const u16* __restrict__ y1, const u16* __restrict__ mP,
           u16* __restrict__ y2)
{
  const int n    = blockIdx.x >> 4;
  const int lt   = blockIdx.x & 15;
  const int tid  = threadIdx.x;
  const int wave = tid >> 6;
  const int lane = tid & 63;
  const int l15  = lane & 15;
  const int g4   = lane >> 4;
  const int colb = lt * 128 + wave * 32;

  const u16* mq = mP + (((size_t)n * 64 * LL + colb + l15) * 4 + g4) * 8;
  const u16* ap = y1 + (size_t)n * CH * LL + (size_t)l15 * LL + g4 * 8;
  u16* o = y2 + (size_t)n * CH * LL + colb + l15;

  f32x4 acc[4][2];
#pragma unroll
  for (int f = 0; f < 4; ++f)
#pragma unroll
    for (int h = 0; h < 2; ++h)
#pragma unroll
      for (int r = 0; r < 4; ++r) acc[f][h][r] = 0.f;

  s16x8 bA0, bA1, bB0, bB1, aA[4], aB[4];

#define K2_LOAD(B0, B1, AV, KB)                                              \
  {                                                                          \
    const u16* _mq = mq + (size_t)(KB) * 65536;                              \
    B0 = *(const s16x8*)(_mq);                                               \
    B1 = *(const s16x8*)(_mq + 512);                                         \
    const u16* _ap = ap + (KB) * 32;                                         \
    _Pragma("unroll") for (int f = 0; f < 4; ++f)                            \
      AV[f] = *(const s16x8*)(_ap + (size_t)(f * 16) * LL);                  \
  }

#define K2_COMP(B0, B1, AV)                                                  \
  _Pragma("unroll") for (int f = 0; f < 4; ++f) {                            \
    acc[f][0] = __builtin_amdgcn_mfma_f32_16x16x32_bf16(AV[f], B0, acc[f][0], 0, 0, 0); \
    acc[f][1] = __builtin_amdgcn_mfma_f32_16x16x32_bf16(AV[f], B1, acc[f][1], 0, 0, 0); \
  }

  K2_LOAD(bA0, bA1, aA, 0)
#pragma unroll 1
  for (int kb = 0; kb < 64; kb += 2) {
    K2_LOAD(bB0, bB1, aB, kb + 1)
    K2_COMP(bA0, bA1, aA)
    if (kb + 2 < 64) K2_LOAD(bA0, bA1, aA, kb + 2)
    K2_COMP(bB0, bB1, aB)
  }

#pragma unroll
  for (int f = 0; f < 4; ++f)
#pragma unroll
    for (int r = 0; r < 4; ++r) {
      const int row = f * 16 + g4 * 4 + r;
      o[(size_t)row * LL]      = f2bf(acc[f][0][r]);
      o[(size_t)row * LL + 16] = f2bf(acc[f][1][r]);
    }
}

// ---------------------------------------------------------------------------
// K3: out[n] (128x2048 fp32) = Wb (128x192) * cat[n] (192x2048) + b
// ---------------------------------------------------------------------------
__global__ __launch_bounds__(256)
void proj(const u16* __restrict__ xb, const u16* __restrict__ y1,
          const u16* __restrict__ y2, const u16* __restrict__ Wb,
          const float* __restrict__ bias, float* __restrict__ out)
{
  const int n    = blockIdx.x >> 4;
  const int lt   = blockIdx.x & 15;
  const int tid  = threadIdx.x;
  const int wave = tid >> 6;
  const int lane = tid & 63;
  const int l15  = lane & 15;
  const int g4   = lane >> 4;
  const int colb = lt * 128 + wave * 32;

  f32x4 acc[8][2];
#pragma unroll
  for (int f = 0; f < 8; ++f)
#pragma unroll
    for (int h = 0; h < 2; ++h)
#pragma unroll
      for (int r = 0; r < 4; ++r) acc[f][h][r] = 0.f;

  const size_t cb = (size_t)n * CH * LL + colb + l15;
  const u16* xp  = xb + cb + (size_t)(g4 * 8) * LL;
  const u16* y1p = y1 + cb + (size_t)(g4 * 8) * LL;
  const u16* y2p = y2 + cb + (size_t)(g4 * 8) * LL;
  const u16* wq  = Wb + (size_t)l15 * 192 + g4 * 8;

#pragma unroll
  for (int kc = 0; kc < 6; ++kc) {
    const int k0 = kc * 32;
    s16x8 b0, b1;
    const u16* src = (k0 < 64) ? (xp + (size_t)k0 * LL)
                   : (k0 < 128) ? (y1p + (size_t)(k0 - 64) * LL)
                                : (y2p + (size_t)(k0 - 128) * LL);
#pragma unroll
    for (int j = 0; j < 8; ++j) {
      b0[j] = (short)src[(size_t)j * LL];
      b1[j] = (short)src[(size_t)j * LL + 16];
    }

#pragma unroll
    for (int f = 0; f < 8; ++f) {
      s16x8 af = *(const s16x8*)(wq + (size_t)(f * 16) * 192 + k0);
      acc[f][0] = __builtin_amdgcn_mfma_f32_16x16x32_bf16(af, b0, acc[f][0], 0, 0, 0);
      acc[f][1] = __builtin_amdgcn_mfma_f32_16x16x32_bf16(af, b1, acc[f][1], 0, 0, 0);
    }
  }

  float* op = out + (size_t)n * OUTC * LL + colb + l15;
#pragma unroll
  for (int f = 0; f < 8; ++f)
#pragma unroll
    for (int r = 0; r < 4; ++r) {
      const int row = f * 16 + g4 * 4 + r;
      op[(size_t)row * LL]      = acc[f][0][r] + bias[row];
      op[(size_t)row * LL + 16] = acc[f][1][r] + bias[row];
    }
}

extern "C" void kernel_launch(void* const* d_in, const int* in_sizes, int n_in,
                              void* d_out, int out_size, void* d_ws, size_t ws_size,
                              hipStream_t stream)
{
  const float* x = (const float*)d_in[0];
  const float* m = (const float*)d_in[1];
  const float* W = (const float*)d_in[2];
  const float* b = (const float*)d_in[3];
  float* out = (float*)d_out;

  // workspace layout (u16 elems): y1 | y2 | xb | Wb | mP
  u16* y1 = (u16*)d_ws;                          //  8 MiB
  u16* y2 = y1 + (size_t)NB * CH * LL;           //  8 MiB
  u16* xb = y2 + (size_t)NB * CH * LL;           //  8 MiB
  u16* Wb = xb + (size_t)NB * CH * LL;           // 48 KiB
  u16* mP = (u16*)((char*)d_ws + (25u << 20));   // 256 MiB, 1 MiB-aligned

  cvt_inputs<<<dim3(2060), dim3(256), 0, stream>>>(x, W, xb, Wb);
  prop1_pack<<<dim3(NB * 16), dim3(256), 0, stream>>>(xb, m, y1, mP);
  prop2<<<dim3(NB * 16), dim3(256), 0, stream>>>(y1, mP, y2);
  proj<<<dim3(NB * 16), dim3(256), 0, stream>>>(xb, y1, y2, Wb, b, out);
}

// Round 6
// 284.444 us; speedup vs baseline: 1.0908x; 1.0908x over previous
//
#include <hip/hip_runtime.h>
#include <hip/hip_bf16.h>

#define NB   32
#define CH   64
#define LL   2048
#define OUTC 128

typedef float  f32x4  __attribute__((ext_vector_type(4)));
typedef short  s16x8  __attribute__((ext_vector_type(8)));
typedef unsigned short u16;

__device__ __forceinline__ u16 f2bf(float f) {
  unsigned int u = __builtin_bit_cast(unsigned int, f);
  u += 0x7FFFu + ((u >> 16) & 1u);           // RNE (scalar epilogue use)
  return (u16)(u >> 16);
}

// 8x fp32 -> 8x bf16 via v_cvt_pk_bf16_f32 (compiler-emitted, RNE)
__device__ __forceinline__ s16x8 pack8c(const float* v) {
  s16x8 r;
#pragma unroll
  for (int j = 0; j < 8; j += 2) {
    __hip_bfloat162 h = __float22bfloat162_rn(make_float2(v[j], v[j + 1]));
    short2 s;
    __builtin_memcpy(&s, &h, sizeof(s));
    r[j] = s.x; r[j + 1] = s.y;
  }
  return r;
}

// ---------------------------------------------------------------------------
// K0: x (fp32->bf16), W (fp32->bf16)
// ---------------------------------------------------------------------------
#define NX (NB * CH * LL)          // 4,194,304
#define NW (OUTC * 3 * CH)         // 24,576
__global__ __launch_bounds__(256)
void cvt_inputs(const float* __restrict__ x, const float* __restrict__ W,
                u16* __restrict__ xb, u16* __restrict__ Wb)
{
  const size_t t8 = ((size_t)blockIdx.x * 256 + threadIdx.x) * 8;
  if (t8 < NX) {
    float v[8];
    *(f32x4*)(v)     = *(const f32x4*)(x + t8);
    *(f32x4*)(v + 4) = *(const f32x4*)(x + t8 + 4);
    *(s16x8*)(xb + t8) = pack8c(v);
  } else if (t8 - NX < NW) {
    const size_t w8 = t8 - NX;
    float v[8];
    *(f32x4*)(v)     = *(const f32x4*)(W + w8);
    *(f32x4*)(v + 4) = *(const f32x4*)(W + w8 + 4);
    *(s16x8*)(Wb + w8) = pack8c(v);
  }
}

// ---------------------------------------------------------------------------
// K1: y1[n] = xb[n] * m[n]  (+ writes mP bf16 B-fragments for K2)
// LDS-staged m tile (coalesced f32x4 global reads, reg-staged double buffer,
// one barrier per K-step). Fragments read from LDS columns; mP pack from regs.
// ---------------------------------------------------------------------------
__global__ __launch_bounds__(256, 2)
void prop1_pack(const u16* __restrict__ xb, const float* __restrict__ m,
                u16* __restrict__ y1, u16* __restrict__ mP)
{
  __shared__ float smem[2][32 * 128];   // 32 KiB, double-buffered 32x128 fp32 tile

  const int n    = blockIdx.x >> 4;
  const int lt   = blockIdx.x & 15;
  const int tid  = threadIdx.x;
  const int wave = tid >> 6;
  const int lane = tid & 63;
  const int l15  = lane & 15;
  const int g4   = lane >> 4;
  const int colb = lt * 128 + wave * 32;

  const float* mn = m  + (size_t)n * LL * LL + lt * 128;   // block's column panel
  const u16*   ap = xb + (size_t)n * CH * LL + (size_t)l15 * LL + g4 * 8;
  u16* q0 = mP + (((size_t)n * 64 * LL + colb + l15) * 4 + g4) * 8; // + kb*65536, h*512
  u16* o  = y1 + (size_t)n * CH * LL + colb + l15;

  f32x4 acc[4][2];
#pragma unroll
  for (int f = 0; f < 4; ++f)
#pragma unroll
    for (int h = 0; h < 2; ++h)
#pragma unroll
      for (int r = 0; r < 4; ++r) acc[f][h][r] = 0.f;

  f32x4 rg[4];   // staging registers: 4 x 16B per thread = one 32x128 fp32 tile/block

  // chunk i: dword offset od = (tid + 256*i)*4 in the 32x128 tile
  //   row = od>>7, coldw = od&127  (coalesced: consecutive tid -> consecutive 16B)
#define LOADR(KB)                                                            \
  { _Pragma("unroll") for (int i = 0; i < 4; ++i) {                          \
      const int _od = (tid + 256 * i) * 4;                                   \
      rg[i] = *(const f32x4*)(mn + (size_t)((KB) * 32 + (_od >> 7)) * LL +   \
                              (_od & 127)); } }

  LOADR(0)
#pragma unroll 1
  for (int kb = 0; kb < 64; ++kb) {
    // write staged tile to LDS (conflict-free b128 pattern), prefetch next
    {
      float* s = smem[kb & 1];
#pragma unroll
      for (int i = 0; i < 4; ++i)
        *(f32x4*)(s + (size_t)(tid + 256 * i) * 4) = rg[i];
    }
    if (kb < 63) LOADR(kb + 1)
    __syncthreads();

    // build B fragments from LDS columns
    const float* t = smem[kb & 1] + wave * 32 + l15;
    float bv0[8], bv1[8];
#pragma unroll
    for (int j = 0; j < 8; ++j) {
      bv0[j] = t[(g4 * 8 + j) * 128];
      bv1[j] = t[(g4 * 8 + j) * 128 + 16];
    }
    s16x8 b0 = pack8c(bv0), b1 = pack8c(bv1);

    // pack m fragments for K2 (coalesced 16B stores)
    u16* q = q0 + (size_t)kb * 65536;
    *(s16x8*)(q)       = b0;
    *(s16x8*)(q + 512) = b1;

    // A fragments + MFMA
    const u16* a_ = ap + kb * 32;
#pragma unroll
    for (int f = 0; f < 4; ++f) {
      s16x8 af = *(const s16x8*)(a_ + (size_t)(f * 16) * LL);
      acc[f][0] = __builtin_amdgcn_mfma_f32_16x16x32_bf16(af, b0, acc[f][0], 0, 0, 0);
      acc[f][1] = __builtin_amdgcn_mfma_f32_16x16x32_bf16(af, b1, acc[f][1], 0, 0, 0);
    }
  }

#pragma unroll
  for (int f = 0; f < 4; ++f)
#pragma unroll
    for (int r = 0; r < 4; ++r) {
      const int row = f * 16 + g4 * 4 + r;
      o[(size_t)row * LL]      = f2bf(acc[f][0][r]);
      o[(size_t)row * LL + 16] = f2bf(acc[f][1][r]);
    }
}

// ---------------------------------------------------------------------------
// K2: y2[n] = y1[n] * m[n], reading mP (pre-packed bf16 fragments).
// ---------------------------------------------------------------------------
__global__ __launch_bounds__(256, 2)
void prop2(const u16* __restrict__ y1, const u16* __restrict__ mP,
           u16* __restrict__ y2)
{
  const int n    = blockIdx.x >> 4;
  const int lt   = blockIdx.x & 15;
  const int tid  = threadIdx.x;
  const int wave = tid >> 6;
  const int lane = tid & 63;
  const int l15  = lane & 15;
  const int g4   = lane >> 4;
  const int colb = lt * 128 + wave * 32;

  const u16* mq = mP + (((size_t)n * 64 * LL + colb + l15) * 4 + g4) * 8;
  const u16* ap = y1 + (size_t)n * CH * LL + (size_t)l15 * LL + g4 * 8;
  u16* o = y2 + (size_t)n * CH * LL + colb + l15;

  f32x4 acc[4][2];
#pragma unroll
  for (int f = 0; f < 4; ++f)
#pragma unroll
    for (int h = 0; h < 2; ++h)
#pragma unroll
      for (int r = 0; r < 4; ++r) acc[f][h][r] = 0.f;

  s16x8 bA0, bA1, bB0, bB1, aA[4], aB[4];

#define K2_LOAD(B0, B1, AV, KB)                                              \
  {                                                                          \
    const u16* _mq = mq + (size_t)(KB) * 65536;                              \
    B0 = *(const s16x8*)(_mq);                                               \
    B1 = *(const s16x8*)(_mq + 512);                                         \
    const u16* _ap = ap + (KB) * 32;                                         \
    _Pragma("unroll") for (int f = 0; f < 4; ++f)                            \
      AV[f] = *(const s16x8*)(_ap + (size_t)(f * 16) * LL);                  \
  }

#define K2_COMP(B0, B1, AV)                                                  \
  _Pragma("unroll") for (int f = 0; f < 4; ++f) {                            \
    acc[f][0] = __builtin_amdgcn_mfma_f32_16x16x32_bf16(AV[f], B0, acc[f][0], 0, 0, 0); \
    acc[f][1] = __builtin_amdgcn_mfma_f32_16x16x32_bf16(AV[f], B1, acc[f][1], 0, 0, 0); \
  }

  K2_LOAD(bA0, bA1, aA, 0)
#pragma unroll 1
  for (int kb = 0; kb < 64; kb += 2) {
    K2_LOAD(bB0, bB1, aB, kb + 1)
    K2_COMP(bA0, bA1, aA)
    if (kb + 2 < 64) K2_LOAD(bA0, bA1, aA, kb + 2)
    K2_COMP(bB0, bB1, aB)
  }

#pragma unroll
  for (int f = 0; f < 4; ++f)
#pragma unroll
    for (int r = 0; r < 4; ++r) {
      const int row = f * 16 + g4 * 4 + r;
      o[(size_t)row * LL]      = f2bf(acc[f][0][r]);
      o[(size_t)row * LL + 16] = f2bf(acc[f][1][r]);
    }
}

// ---------------------------------------------------------------------------
// K3: out[n] (128x2048 fp32) = Wb (128x192) * cat[n] (192x2048) + b
// ---------------------------------------------------------------------------
__global__ __launch_bounds__(256)
void proj(const u16* __restrict__ xb, const u16* __restrict__ y1,
          const u16* __restrict__ y2, const u16* __restrict__ Wb,
          const float* __restrict__ bias, float* __restrict__ out)
{
  const int n    = blockIdx.x >> 4;
  const int lt   = blockIdx.x & 15;
  const int tid  = threadIdx.x;
  const int wave = tid >> 6;
  const int lane = tid & 63;
  const int l15  = lane & 15;
  const int g4   = lane >> 4;
  const int colb = lt * 128 + wave * 32;

  f32x4 acc[8][2];
#pragma unroll
  for (int f = 0; f < 8; ++f)
#pragma unroll
    for (int h = 0; h < 2; ++h)
#pragma unroll
      for (int r = 0; r < 4; ++r) acc[f][h][r] = 0.f;

  const size_t cb = (size_t)n * CH * LL + colb + l15;
  const u16* xp  = xb + cb + (size_t)(g4 * 8) * LL;
  const u16* y1p = y1 + cb + (size_t)(g4 * 8) * LL;
  const u16* y2p = y2 + cb + (size_t)(g4 * 8) * LL;
  const u16* wq  = Wb + (size_t)l15 * 192 + g4 * 8;

#pragma unroll
  for (int kc = 0; kc < 6; ++kc) {
    const int k0 = kc * 32;
    s16x8 b0, b1;
    const u16* src = (k0 < 64) ? (xp + (size_t)k0 * LL)
                   : (k0 < 128) ? (y1p + (size_t)(k0 - 64) * LL)
                                : (y2p + (size_t)(k0 - 128) * LL);
#pragma unroll
    for (int j = 0; j < 8; ++j) {
      b0[j] = (short)src[(size_t)j * LL];
      b1[j] = (short)src[(size_t)j * LL + 16];
    }

#pragma unroll
    for (int f = 0; f < 8; ++f) {
      s16x8 af = *(const s16x8*)(wq + (size_t)(f * 16) * 192 + k0);
      acc[f][0] = __builtin_amdgcn_mfma_f32_16x16x32_bf16(af, b0, acc[f][0], 0, 0, 0);
      acc[f][1] = __builtin_amdgcn_mfma_f32_16x16x32_bf16(af, b1, acc[f][1], 0, 0, 0);
    }
  }

  float* op = out + (size_t)n * OUTC * LL + colb + l15;
#pragma unroll
  for (int f = 0; f < 8; ++f)
#pragma unroll
    for (int r = 0; r < 4; ++r) {
      const int row = f * 16 + g4 * 4 + r;
      op[(size_t)row * LL]      = acc[f][0][r] + bias[row];
      op[(size_t)row * LL + 16] = acc[f][1][r] + bias[row];
    }
}

extern "C" void kernel_launch(void* const* d_in, const int* in_sizes, int n_in,
                              void* d_out, int out_size, void* d_ws, size_t ws_size,
                              hipStream_t stream)
{
  const float* x = (const float*)d_in[0];
  const float* m = (const float*)d_in[1];
  const float* W = (const float*)d_in[2];
  const float* b = (const float*)d_in[3];
  float* out = (float*)d_out;

  // workspace layout (u16 elems): y1 | y2 | xb | Wb | mP
  u16* y1 = (u16*)d_ws;                          //  8 MiB
  u16* y2 = y1 + (size_t)NB * CH * LL;           //  8 MiB
  u16* xb = y2 + (size_t)NB * CH * LL;           //  8 MiB
  u16* Wb = xb + (size_t)NB * CH * LL;           // 48 KiB
  u16* mP = (u16*)((char*)d_ws + (25u << 20));   // 256 MiB, 1 MiB-aligned

  cvt_inputs<<<dim3(2060), dim3(256), 0, stream>>>(x, W, xb, Wb);
  prop1_pack<<<dim3(NB * 16), dim3(256), 0, stream>>>(xb, m, y1, mP);
  prop2<<<dim3(NB * 16), dim3(256), 0, stream>>>(y1, mP, y2);
  proj<<<dim3(NB * 16), dim3(256), 0, stream>>>(xb, y1, y2, Wb, b, out);
}

// Round 7
// 279.560 us; speedup vs baseline: 1.1099x; 1.0175x over previous
//
#include <hip/hip_runtime.h>
#include <hip/hip_bf16.h>

#define NB   32
#define CH   64
#define LL   2048
#define OUTC 128

typedef float  f32x4  __attribute__((ext_vector_type(4)));
typedef short  s16x8  __attribute__((ext_vector_type(8)));
typedef short  s16x4  __attribute__((ext_vector_type(4)));
typedef unsigned short u16;

__device__ __forceinline__ u16 f2bf(float f) {
  unsigned int u = __builtin_bit_cast(unsigned int, f);
  u += 0x7FFFu + ((u >> 16) & 1u);           // RNE (scalar epilogue use)
  return (u16)(u >> 16);
}

// 8x fp32 -> 8x bf16 via v_cvt_pk_bf16_f32 (compiler-emitted, RNE)
__device__ __forceinline__ s16x8 pack8c(const float* v) {
  s16x8 r;
#pragma unroll
  for (int j = 0; j < 8; j += 2) {
    __hip_bfloat162 h = __float22bfloat162_rn(make_float2(v[j], v[j + 1]));
    short2 s;
    __builtin_memcpy(&s, &h, sizeof(s));
    r[j] = s.x; r[j + 1] = s.y;
  }
  return r;
}

__device__ __forceinline__ s16x4 pack4c(const f32x4& v) {
  s16x4 r;
  __hip_bfloat162 h0 = __float22bfloat162_rn(make_float2(v[0], v[1]));
  __hip_bfloat162 h1 = __float22bfloat162_rn(make_float2(v[2], v[3]));
  short2 s0, s1;
  __builtin_memcpy(&s0, &h0, sizeof(s0));
  __builtin_memcpy(&s1, &h1, sizeof(s1));
  r[0] = s0.x; r[1] = s0.y; r[2] = s1.x; r[3] = s1.y;
  return r;
}

// ---------------------------------------------------------------------------
// K0: x (fp32->bf16), W (fp32->bf16)
// ---------------------------------------------------------------------------
#define NX (NB * CH * LL)          // 4,194,304
#define NW (OUTC * 3 * CH)         // 24,576
__global__ __launch_bounds__(256)
void cvt_inputs(const float* __restrict__ x, const float* __restrict__ W,
                u16* __restrict__ xb, u16* __restrict__ Wb)
{
  const size_t t8 = ((size_t)blockIdx.x * 256 + threadIdx.x) * 8;
  if (t8 < NX) {
    float v[8];
    *(f32x4*)(v)     = *(const f32x4*)(x + t8);
    *(f32x4*)(v + 4) = *(const f32x4*)(x + t8 + 4);
    *(s16x8*)(xb + t8) = pack8c(v);
  } else if (t8 - NX < NW) {
    const size_t w8 = t8 - NX;
    float v[8];
    *(f32x4*)(v)     = *(const f32x4*)(W + w8);
    *(f32x4*)(v + 4) = *(const f32x4*)(W + w8 + 4);
    *(s16x8*)(Wb + w8) = pack8c(v);
  }
}

// ---------------------------------------------------------------------------
// K1: y1[n] = xb[n] * m[n]  (+ writes mP bf16 B-fragments for K2)
// global_load_lds (16B) into 3 LDS buffers; counted vmcnt + raw s_barrier so
// prefetch loads stay in flight ACROSS barriers (no vmcnt(0) drain).
// ---------------------------------------------------------------------------
__global__ __launch_bounds__(256, 2)
void prop1_pack(const u16* __restrict__ xb, const float* __restrict__ m,
                u16* __restrict__ y1, u16* __restrict__ mP)
{
  __shared__ float smem[3][32 * 128];   // 48 KiB triple-buffered 32x128 fp32 tile

  const int n    = blockIdx.x >> 4;
  const int lt   = blockIdx.x & 15;
  const int tid  = threadIdx.x;
  const int wave = tid >> 6;
  const int lane = tid & 63;
  const int l15  = lane & 15;
  const int g4   = lane >> 4;
  const int colb = lt * 128 + wave * 32;

  const float* mn = m + (size_t)n * LL * LL + lt * 128;
  // gload chunk i of a tile: wave-uniform LDS base (wave*4+i)*1024B; lane l
  // covers dwords (wave*4+i)*256 + l*4 -> row=(wave*4+i)*2+(l>>5), col=(l&31)*4
  const float* gsrc = mn + (size_t)(wave * 8 + (lane >> 5)) * LL + (lane & 31) * 4;

  const u16* ap = xb + (size_t)n * CH * LL + (size_t)l15 * LL + g4 * 8;
  u16* q0 = mP + (((size_t)n * 64 * LL + colb + l15) * 4 + g4) * 8; // + kb*65536, h*512
  u16* o  = y1 + (size_t)n * CH * LL + colb + l15;

  f32x4 acc[4][2];
#pragma unroll
  for (int f = 0; f < 4; ++f)
#pragma unroll
    for (int h = 0; h < 2; ++h)
#pragma unroll
      for (int r = 0; r < 4; ++r) acc[f][h][r] = 0.f;

#define GLOAD(SB, KB)                                                         \
  { float* _sb = (SB);                                                        \
    _Pragma("unroll") for (int i = 0; i < 4; ++i) {                           \
      const float* _g = gsrc + (size_t)((KB) * 32 + i * 2) * LL;              \
      __builtin_amdgcn_global_load_lds(                                       \
        (const __attribute__((address_space(1))) void*)_g,                    \
        (__attribute__((address_space(3))) void*)(_sb + (wave * 4 + i) * 256),\
        16, 0, 0); } }

  GLOAD(smem[0], 0)
  GLOAD(smem[1], 1)
  asm volatile("s_waitcnt vmcnt(4)" ::: "memory");   // tile 0 landed
  __builtin_amdgcn_s_barrier();
  __builtin_amdgcn_sched_barrier(0);

  int bc = 0;   // buffer holding tile kb
#pragma unroll 1
  for (int kb = 0; kb < 64; ++kb) {
    // A fragments FIRST (oldest vmem this step -> MFMA auto-wait won't drain prefetch)
    s16x8 a[4];
    const u16* a_ = ap + kb * 32;
#pragma unroll
    for (int f = 0; f < 4; ++f) a[f] = *(const s16x8*)(a_ + (size_t)(f * 16) * LL);
    __builtin_amdgcn_sched_barrier(0);

    // prefetch tile kb+2 into the buffer freed two steps ago
    const int b2 = (bc == 0) ? 2 : bc - 1;   // (bc+2)%3
    if (kb + 2 < 64) GLOAD(smem[b2], kb + 2)

    // B fragments from LDS columns
    const float* t = smem[bc] + wave * 32 + l15;
    float bv0[8], bv1[8];
#pragma unroll
    for (int j = 0; j < 8; ++j) {
      bv0[j] = t[(g4 * 8 + j) * 128];
      bv1[j] = t[(g4 * 8 + j) * 128 + 16];
    }
    s16x8 b0 = pack8c(bv0), b1 = pack8c(bv1);

    // pack m fragments for K2 (coalesced 16B stores)
    u16* q = q0 + (size_t)kb * 65536;
    *(s16x8*)(q)       = b0;
    *(s16x8*)(q + 512) = b1;

#pragma unroll
    for (int f = 0; f < 4; ++f) {
      acc[f][0] = __builtin_amdgcn_mfma_f32_16x16x32_bf16(a[f], b0, acc[f][0], 0, 0, 0);
      acc[f][1] = __builtin_amdgcn_mfma_f32_16x16x32_bf16(a[f], b1, acc[f][1], 0, 0, 0);
    }

    if (kb + 1 < 64) {
      // retire tile kb+1's 4 gloads; keep kb+2's 4 gloads + 2 stores in flight
      asm volatile("s_waitcnt vmcnt(6)" ::: "memory");
      __builtin_amdgcn_s_barrier();
      __builtin_amdgcn_sched_barrier(0);
    }
    bc = (bc == 2) ? 0 : bc + 1;
  }

#pragma unroll
  for (int f = 0; f < 4; ++f)
#pragma unroll
    for (int r = 0; r < 4; ++r) {
      const int row = f * 16 + g4 * 4 + r;
      o[(size_t)row * LL]      = f2bf(acc[f][0][r]);
      o[(size_t)row * LL + 16] = f2bf(acc[f][1][r]);
    }
}

// ---------------------------------------------------------------------------
// K2: y2 = y1 * m (from mP) FUSED with projection epilogue:
//     out[n] = Wb * [xb; y1; y2] + b.  y2 never touches HBM (LDS transpose).
// ---------------------------------------------------------------------------
__global__ __launch_bounds__(256, 2)
void prop2_proj(const u16* __restrict__ y1, const u16* __restrict__ mP,
                const u16* __restrict__ xb, const u16* __restrict__ Wb,
                const float* __restrict__ bias, float* __restrict__ out)
{
  __shared__ u16 yT[128 * 72];   // col-major y2 tile: yT[col*72 + row], 18 KiB

  const int n    = blockIdx.x >> 4;
  const int lt   = blockIdx.x & 15;
  const int tid  = threadIdx.x;
  const int wave = tid >> 6;
  const int lane = tid & 63;
  const int l15  = lane & 15;
  const int g4   = lane >> 4;
  const int colb = lt * 128 + wave * 32;

  const u16* mq = mP + (((size_t)n * 64 * LL + colb + l15) * 4 + g4) * 8;
  const u16* ap = y1 + (size_t)n * CH * LL + (size_t)l15 * LL + g4 * 8;

  f32x4 acc[4][2];
#pragma unroll
  for (int f = 0; f < 4; ++f)
#pragma unroll
    for (int h = 0; h < 2; ++h)
#pragma unroll
      for (int r = 0; r < 4; ++r) acc[f][h][r] = 0.f;

  s16x8 bA0, bA1, bB0, bB1, aA[4], aB[4];

#define K2_LOAD(B0, B1, AV, KB)                                              \
  {                                                                          \
    const u16* _mq = mq + (size_t)(KB) * 65536;                              \
    B0 = *(const s16x8*)(_mq);                                               \
    B1 = *(const s16x8*)(_mq + 512);                                         \
    const u16* _ap = ap + (KB) * 32;                                         \
    _Pragma("unroll") for (int f = 0; f < 4; ++f)                            \
      AV[f] = *(const s16x8*)(_ap + (size_t)(f * 16) * LL);                  \
  }

#define K2_COMP(B0, B1, AV)                                                  \
  _Pragma("unroll") for (int f = 0; f < 4; ++f) {                            \
    acc[f][0] = __builtin_amdgcn_mfma_f32_16x16x32_bf16(AV[f], B0, acc[f][0], 0, 0, 0); \
    acc[f][1] = __builtin_amdgcn_mfma_f32_16x16x32_bf16(AV[f], B1, acc[f][1], 0, 0, 0); \
  }

  K2_LOAD(bA0, bA1, aA, 0)
#pragma unroll 1
  for (int kb = 0; kb < 64; kb += 2) {
    K2_LOAD(bB0, bB1, aB, kb + 1)
    K2_COMP(bA0, bA1, aA)
    if (kb + 2 < 64) K2_LOAD(bA0, bA1, aA, kb + 2)
    K2_COMP(bB0, bB1, aB)
  }

  // ---- epilogue: y2 (acc) -> LDS col-major bf16 ----
#pragma unroll
  for (int f = 0; f < 4; ++f)
#pragma unroll
    for (int h = 0; h < 2; ++h) {
      const int c = wave * 32 + l15 + 16 * h;
      *(s16x4*)(&yT[c * 72 + f * 16 + g4 * 4]) = pack4c(acc[f][h]);
    }
  __syncthreads();

  // ---- projection: out = Wb(128x192) * [xb;y1;y2] + b ----
  f32x4 acc2[8][2];
#pragma unroll
  for (int f = 0; f < 8; ++f)
#pragma unroll
    for (int h = 0; h < 2; ++h)
#pragma unroll
      for (int r = 0; r < 4; ++r) acc2[f][h][r] = 0.f;

  const size_t cb = (size_t)n * CH * LL + colb + l15;
  const u16* xp  = xb + cb + (size_t)(g4 * 8) * LL;
  const u16* y1p = y1 + cb + (size_t)(g4 * 8) * LL;
  const u16* wq  = Wb + (size_t)l15 * 192 + g4 * 8;

#pragma unroll
  for (int kc = 0; kc < 6; ++kc) {
    const int k0 = kc * 32;
    s16x8 b0, b1;
    if (kc < 4) {
      const u16* src = (kc < 2) ? (xp + (size_t)k0 * LL)
                                : (y1p + (size_t)(k0 - 64) * LL);
#pragma unroll
      for (int j = 0; j < 8; ++j) {
        b0[j] = (short)src[(size_t)j * LL];
        b1[j] = (short)src[(size_t)j * LL + 16];
      }
    } else {
      const int rb = (kc - 4) * 32 + g4 * 8;
      b0 = *(const s16x8*)(&yT[(wave * 32 + l15) * 72 + rb]);
      b1 = *(const s16x8*)(&yT[(wave * 32 + l15 + 16) * 72 + rb]);
    }
#pragma unroll
    for (int f = 0; f < 8; ++f) {
      s16x8 af = *(const s16x8*)(wq + (size_t)(f * 16) * 192 + k0);
      acc2[f][0] = __builtin_amdgcn_mfma_f32_16x16x32_bf16(af, b0, acc2[f][0], 0, 0, 0);
      acc2[f][1] = __builtin_amdgcn_mfma_f32_16x16x32_bf16(af, b1, acc2[f][1], 0, 0, 0);
    }
  }

  float* op = out + (size_t)n * OUTC * LL + colb + l15;
#pragma unroll
  for (int f = 0; f < 8; ++f)
#pragma unroll
    for (int r = 0; r < 4; ++r) {
      const int row = f * 16 + g4 * 4 + r;
      op[(size_t)row * LL]      = acc2[f][0][r] + bias[row];
      op[(size_t)row * LL + 16] = acc2[f][1][r] + bias[row];
    }
}

extern "C" void kernel_launch(void* const* d_in, const int* in_sizes, int n_in,
                              void* d_out, int out_size, void* d_ws, size_t ws_size,
                              hipStream_t stream)
{
  const float* x = (const float*)d_in[0];
  const float* m = (const float*)d_in[1];
  const float* W = (const float*)d_in[2];
  const float* b = (const float*)d_in[3];
  float* out = (float*)d_out;

  // workspace layout (u16 elems): y1 | xb | Wb | mP
  u16* y1 = (u16*)d_ws;                          //  8 MiB
  u16* xb = y1 + (size_t)NB * CH * LL;           //  8 MiB
  u16* Wb = xb + (size_t)NB * CH * LL;           // 48 KiB
  u16* mP = (u16*)((char*)d_ws + (25u << 20));   // 268 MiB, 1 MiB-aligned

  cvt_inputs<<<dim3(2060), dim3(256), 0, stream>>>(x, W, xb, Wb);
  prop1_pack<<<dim3(NB * 16), dim3(256), 0, stream>>>(xb, m, y1, mP);
  prop2_proj<<<dim3(NB * 16), dim3(256), 0, stream>>>(y1, mP, xb, Wb, b, out);
}

// Round 8
// 271.663 us; speedup vs baseline: 1.1421x; 1.0291x over previous
//
#include <hip/hip_runtime.h>
#include <hip/hip_bf16.h>

#define NB   32
#define CH   64
#define LL   2048
#define OUTC 128

typedef float  f32x4  __attribute__((ext_vector_type(4)));
typedef short  s16x8  __attribute__((ext_vector_type(8)));
typedef short  s16x4  __attribute__((ext_vector_type(4)));
typedef unsigned short u16;

__device__ __forceinline__ u16 f2bf(float f) {
  unsigned int u = __builtin_bit_cast(unsigned int, f);
  u += 0x7FFFu + ((u >> 16) & 1u);           // RNE (scalar epilogue use)
  return (u16)(u >> 16);
}

// 8x fp32 -> 8x bf16 via v_cvt_pk_bf16_f32 (compiler-emitted, RNE)
__device__ __forceinline__ s16x8 pack8c(const float* v) {
  s16x8 r;
#pragma unroll
  for (int j = 0; j < 8; j += 2) {
    __hip_bfloat162 h = __float22bfloat162_rn(make_float2(v[j], v[j + 1]));
    short2 s;
    __builtin_memcpy(&s, &h, sizeof(s));
    r[j] = s.x; r[j + 1] = s.y;
  }
  return r;
}

__device__ __forceinline__ s16x4 pack4c(const f32x4& v) {
  s16x4 r;
  __hip_bfloat162 h0 = __float22bfloat162_rn(make_float2(v[0], v[1]));
  __hip_bfloat162 h1 = __float22bfloat162_rn(make_float2(v[2], v[3]));
  short2 s0, s1;
  __builtin_memcpy(&s0, &h0, sizeof(s0));
  __builtin_memcpy(&s1, &h1, sizeof(s1));
  r[0] = s0.x; r[1] = s0.y; r[2] = s1.x; r[3] = s1.y;
  return r;
}

// ---------------------------------------------------------------------------
// K0: x (fp32->bf16), W (fp32->bf16)
// ---------------------------------------------------------------------------
#define NX (NB * CH * LL)          // 4,194,304
#define NW (OUTC * 3 * CH)         // 24,576
__global__ __launch_bounds__(256)
void cvt_inputs(const float* __restrict__ x, const float* __restrict__ W,
                u16* __restrict__ xb, u16* __restrict__ Wb)
{
  const size_t t8 = ((size_t)blockIdx.x * 256 + threadIdx.x) * 8;
  if (t8 < NX) {
    float v[8];
    *(f32x4*)(v)     = *(const f32x4*)(x + t8);
    *(f32x4*)(v + 4) = *(const f32x4*)(x + t8 + 4);
    *(s16x8*)(xb + t8) = pack8c(v);
  } else if (t8 - NX < NW) {
    const size_t w8 = t8 - NX;
    float v[8];
    *(f32x4*)(v)     = *(const f32x4*)(W + w8);
    *(f32x4*)(v + 4) = *(const f32x4*)(W + w8 + 4);
    *(s16x8*)(Wb + w8) = pack8c(v);
  }
}

// ---------------------------------------------------------------------------
// K1: y1[n] = xb[n] * m[n]  (+ writes mP bf16 B-fragments for K2)
// Quad-buffered gload_lds pipeline, prefetch distance 3; A-fragments
// register-prefetched distance 1 and issued BEFORE the GLOADs so the
// compiler's MFMA wait (vmcnt(16)) never drains the m-tile stream.
// Per-iter issue: [A:4][G:4][St:2]; steady barrier wait = vmcnt(22).
// ---------------------------------------------------------------------------
__global__ __launch_bounds__(256, 2)
void prop1_pack(const u16* __restrict__ xb, const float* __restrict__ m,
                u16* __restrict__ y1, u16* __restrict__ mP)
{
  __shared__ float smem[4][32 * 128];   // 64 KiB quad-buffered 32x128 fp32 tile

  const int n    = blockIdx.x >> 4;
  const int lt   = blockIdx.x & 15;
  const int tid  = threadIdx.x;
  const int wave = tid >> 6;
  const int lane = tid & 63;
  const int l15  = lane & 15;
  const int g4   = lane >> 4;
  const int colb = lt * 128 + wave * 32;

  const float* mn   = m + (size_t)n * LL * LL + lt * 128;
  const float* gsrc = mn + (size_t)(wave * 8 + (lane >> 5)) * LL + (lane & 31) * 4;
  const u16*   ap   = xb + (size_t)n * CH * LL + (size_t)l15 * LL + g4 * 8;
  u16* q0 = mP + (((size_t)n * 64 * LL + colb + l15) * 4 + g4) * 8; // + kb*65536, h*512
  u16* o  = y1 + (size_t)n * CH * LL + colb + l15;

  f32x4 acc[4][2];
#pragma unroll
  for (int f = 0; f < 4; ++f)
#pragma unroll
    for (int h = 0; h < 2; ++h)
#pragma unroll
      for (int r = 0; r < 4; ++r) acc[f][h][r] = 0.f;

  s16x8 aP[4], aQ[4];

#define ALOAD(R, KB)                                                          \
  { const u16* _ap = ap + (KB) * 32;                                          \
    _Pragma("unroll") for (int f = 0; f < 4; ++f)                             \
      R[f] = *(const s16x8*)(_ap + (size_t)(f * 16) * LL); }

#define GLOAD(BI, KB)                                                         \
  { float* _sb = smem[BI];                                                    \
    _Pragma("unroll") for (int i = 0; i < 4; ++i) {                           \
      const float* _g = gsrc + (size_t)((KB) * 32 + i * 2) * LL;              \
      __builtin_amdgcn_global_load_lds(                                       \
        (const __attribute__((address_space(1))) void*)_g,                    \
        (__attribute__((address_space(3))) void*)(_sb + (wave * 4 + i) * 256),\
        16, 0, 0); } }

  // prologue: A(0) FIRST (oldest), then tiles 0,1,2
  ALOAD(aP, 0)
  __builtin_amdgcn_sched_barrier(0);
  GLOAD(0, 0) GLOAD(1, 1) GLOAD(2, 2)
  __builtin_amdgcn_sched_barrier(0);
  asm volatile("s_waitcnt vmcnt(8)" ::: "memory");   // tile 0 landed (G1+G2 = 8 newer)
  __builtin_amdgcn_s_barrier();
  __builtin_amdgcn_sched_barrier(0);

  // one K-step. Issue order: A(kb+1) | G(kb+3) | ds_read/pack/store/MFMA | wait+barrier
#define K1_STEP(KB, CUR, NXT, VN, LAST)                                       \
  {                                                                           \
    if (!(LAST)) {                                                            \
      ALOAD(NXT, ((KB) + 1 < 64 ? (KB) + 1 : 63))                             \
      __builtin_amdgcn_sched_barrier(0);                                      \
      GLOAD(((KB) + 3) & 3, ((KB) + 3 < 64 ? (KB) + 3 : 63))                  \
      __builtin_amdgcn_sched_barrier(0);                                      \
    }                                                                         \
    const float* _t = smem[(KB) & 3] + wave * 32 + l15;                       \
    float _bv0[8], _bv1[8];                                                   \
    _Pragma("unroll") for (int j = 0; j < 8; ++j) {                           \
      _bv0[j] = _t[(g4 * 8 + j) * 128];                                       \
      _bv1[j] = _t[(g4 * 8 + j) * 128 + 16];                                  \
    }                                                                         \
    s16x8 _b0 = pack8c(_bv0), _b1 = pack8c(_bv1);                             \
    u16* _q = q0 + (size_t)(KB) * 65536;                                      \
    *(s16x8*)(_q)       = _b0;                                                \
    *(s16x8*)(_q + 512) = _b1;                                                \
    _Pragma("unroll") for (int f = 0; f < 4; ++f) {                           \
      acc[f][0] = __builtin_amdgcn_mfma_f32_16x16x32_bf16(CUR[f], _b0, acc[f][0], 0, 0, 0); \
      acc[f][1] = __builtin_amdgcn_mfma_f32_16x16x32_bf16(CUR[f], _b1, acc[f][1], 0, 0, 0); \
    }                                                                         \
    if (!(LAST)) {                                                            \
      __builtin_amdgcn_sched_barrier(0);                                      \
      asm volatile("s_waitcnt vmcnt(" VN ")" ::: "memory");                   \
      __builtin_amdgcn_s_barrier();                                           \
      __builtin_amdgcn_sched_barrier(0);                                      \
    }                                                                         \
  }

  K1_STEP(0, aP, aQ, "14", false)   // retire G(1): G2+A1+G3+St0 = 14 newer
  K1_STEP(1, aQ, aP, "20", false)   // retire G(2): 20 newer
#pragma unroll 1
  for (int kb = 2; kb < 62; kb += 2) {
    K1_STEP(kb,     aP, aQ, "22", false)
    K1_STEP(kb + 1, aQ, aP, "22", false)
  }
  K1_STEP(62, aP, aQ, "22", false)
  K1_STEP(63, aQ, aP, "0",  true)

#pragma unroll
  for (int f = 0; f < 4; ++f)
#pragma unroll
    for (int r = 0; r < 4; ++r) {
      const int row = f * 16 + g4 * 4 + r;
      o[(size_t)row * LL]      = f2bf(acc[f][0][r]);
      o[(size_t)row * LL + 16] = f2bf(acc[f][1][r]);
    }
}

// ---------------------------------------------------------------------------
// K2: y2 = y1 * m (from mP) FUSED with projection epilogue:
//     out[n] = Wb * [xb; y1; y2] + b.  y2 never touches HBM (LDS transpose).
// ---------------------------------------------------------------------------
__global__ __launch_bounds__(256, 2)
void prop2_proj(const u16* __restrict__ y1, const u16* __restrict__ mP,
                const u16* __restrict__ xb, const u16* __restrict__ Wb,
                const float* __restrict__ bias, float* __restrict__ out)
{
  __shared__ u16 yT[128 * 72];   // col-major y2 tile: yT[col*72 + row], 18 KiB

  const int n    = blockIdx.x >> 4;
  const int lt   = blockIdx.x & 15;
  const int tid  = threadIdx.x;
  const int wave = tid >> 6;
  const int lane = tid & 63;
  const int l15  = lane & 15;
  const int g4   = lane >> 4;
  const int colb = lt * 128 + wave * 32;

  const u16* mq = mP + (((size_t)n * 64 * LL + colb + l15) * 4 + g4) * 8;
  const u16* ap = y1 + (size_t)n * CH * LL + (size_t)l15 * LL + g4 * 8;

  f32x4 acc[4][2];
#pragma unroll
  for (int f = 0; f < 4; ++f)
#pragma unroll
    for (int h = 0; h < 2; ++h)
#pragma unroll
      for (int r = 0; r < 4; ++r) acc[f][h][r] = 0.f;

  s16x8 bA0, bA1, bB0, bB1, aA[4], aB[4];

#define K2_LOAD(B0, B1, AV, KB)                                              \
  {                                                                          \
    const u16* _mq = mq + (size_t)(KB) * 65536;                              \
    B0 = *(const s16x8*)(_mq);                                               \
    B1 = *(const s16x8*)(_mq + 512);                                         \
    const u16* _ap = ap + (KB) * 32;                                         \
    _Pragma("unroll") for (int f = 0; f < 4; ++f)                            \
      AV[f] = *(const s16x8*)(_ap + (size_t)(f * 16) * LL);                  \
  }

#define K2_COMP(B0, B1, AV)                                                  \
  _Pragma("unroll") for (int f = 0; f < 4; ++f) {                            \
    acc[f][0] = __builtin_amdgcn_mfma_f32_16x16x32_bf16(AV[f], B0, acc[f][0], 0, 0, 0); \
    acc[f][1] = __builtin_amdgcn_mfma_f32_16x16x32_bf16(AV[f], B1, acc[f][1], 0, 0, 0); \
  }

  K2_LOAD(bA0, bA1, aA, 0)
#pragma unroll 1
  for (int kb = 0; kb < 64; kb += 2) {
    K2_LOAD(bB0, bB1, aB, kb + 1)
    K2_COMP(bA0, bA1, aA)
    if (kb + 2 < 64) K2_LOAD(bA0, bA1, aA, kb + 2)
    K2_COMP(bB0, bB1, aB)
  }

  // ---- epilogue: y2 (acc) -> LDS col-major bf16 ----
#pragma unroll
  for (int f = 0; f < 4; ++f)
#pragma unroll
    for (int h = 0; h < 2; ++h) {
      const int c = wave * 32 + l15 + 16 * h;
      *(s16x4*)(&yT[c * 72 + f * 16 + g4 * 4]) = pack4c(acc[f][h]);
    }
  __syncthreads();

  // ---- projection: out = Wb(128x192) * [xb;y1;y2] + b ----
  f32x4 acc2[8][2];
#pragma unroll
  for (int f = 0; f < 8; ++f)
#pragma unroll
    for (int h = 0; h < 2; ++h)
#pragma unroll
      for (int r = 0; r < 4; ++r) acc2[f][h][r] = 0.f;

  const size_t cb = (size_t)n * CH * LL + colb + l15;
  const u16* xp  = xb + cb + (size_t)(g4 * 8) * LL;
  const u16* y1p = y1 + cb + (size_t)(g4 * 8) * LL;
  const u16* wq  = Wb + (size_t)l15 * 192 + g4 * 8;

#pragma unroll
  for (int kc = 0; kc < 6; ++kc) {
    const int k0 = kc * 32;
    s16x8 b0, b1;
    if (kc < 4) {
      const u16* src = (kc < 2) ? (xp + (size_t)k0 * LL)
                                : (y1p + (size_t)(k0 - 64) * LL);
#pragma unroll
      for (int j = 0; j < 8; ++j) {
        b0[j] = (short)src[(size_t)j * LL];
        b1[j] = (short)src[(size_t)j * LL + 16];
      }
    } else {
      const int rb = (kc - 4) * 32 + g4 * 8;
      b0 = *(const s16x8*)(&yT[(wave * 32 + l15) * 72 + rb]);
      b1 = *(const s16x8*)(&yT[(wave * 32 + l15 + 16) * 72 + rb]);
    }
#pragma unroll
    for (int f = 0; f < 8; ++f) {
      s16x8 af = *(const s16x8*)(wq + (size_t)(f * 16) * 192 + k0);
      acc2[f][0] = __builtin_amdgcn_mfma_f32_16x16x32_bf16(af, b0, acc2[f][0], 0, 0, 0);
      acc2[f][1] = __builtin_amdgcn_mfma_f32_16x16x32_bf16(af, b1, acc2[f][1], 0, 0, 0);
    }
  }

  float* op = out + (size_t)n * OUTC * LL + colb + l15;
#pragma unroll
  for (int f = 0; f < 8; ++f)
#pragma unroll
    for (int r = 0; r < 4; ++r) {
      const int row = f * 16 + g4 * 4 + r;
      op[(size_t)row * LL]      = acc2[f][0][r] + bias[row];
      op[(size_t)row * LL + 16] = acc2[f][1][r] + bias[row];
    }
}

extern "C" void kernel_launch(void* const* d_in, const int* in_sizes, int n_in,
                              void* d_out, int out_size, void* d_ws, size_t ws_size,
                              hipStream_t stream)
{
  const float* x = (const float*)d_in[0];
  const float* m = (const float*)d_in[1];
  const float* W = (const float*)d_in[2];
  const float* b = (const float*)d_in[3];
  float* out = (float*)d_out;

  // workspace layout (u16 elems): y1 | xb | Wb | mP
  u16* y1 = (u16*)d_ws;                          //  8 MiB
  u16* xb = y1 + (size_t)NB * CH * LL;           //  8 MiB
  u16* Wb = xb + (size_t)NB * CH * LL;           // 48 KiB
  u16* mP = (u16*)((char*)d_ws + (25u << 20));   // 268 MiB, 1 MiB-aligned

  cvt_inputs<<<dim3(2060), dim3(256), 0, stream>>>(x, W, xb, Wb);
  prop1_pack<<<dim3(NB * 16), dim3(256), 0, stream>>>(xb, m, y1, mP);
  prop2_proj<<<dim3(NB * 16), dim3(256), 0, stream>>>(y1, mP, xb, Wb, b, out);
}

// Round 9
// 271.542 us; speedup vs baseline: 1.1426x; 1.0004x over previous
//
#include <hip/hip_runtime.h>
#include <hip/hip_bf16.h>

#define NB   32
#define CH   64
#define LL   2048
#define OUTC 128

typedef float  f32x4  __attribute__((ext_vector_type(4)));
typedef short  s16x8  __attribute__((ext_vector_type(8)));
typedef short  s16x4  __attribute__((ext_vector_type(4)));
typedef unsigned short u16;

__device__ __forceinline__ u16 f2bf(float f) {
  unsigned int u = __builtin_bit_cast(unsigned int, f);
  u += 0x7FFFu + ((u >> 16) & 1u);           // RNE (scalar epilogue use)
  return (u16)(u >> 16);
}

// 8x fp32 -> 8x bf16 via v_cvt_pk_bf16_f32 (compiler-emitted, RNE)
__device__ __forceinline__ s16x8 pack8c(const float* v) {
  s16x8 r;
#pragma unroll
  for (int j = 0; j < 8; j += 2) {
    __hip_bfloat162 h = __float22bfloat162_rn(make_float2(v[j], v[j + 1]));
    short2 s;
    __builtin_memcpy(&s, &h, sizeof(s));
    r[j] = s.x; r[j + 1] = s.y;
  }
  return r;
}

__device__ __forceinline__ s16x4 pack4c(const f32x4& v) {
  s16x4 r;
  __hip_bfloat162 h0 = __float22bfloat162_rn(make_float2(v[0], v[1]));
  __hip_bfloat162 h1 = __float22bfloat162_rn(make_float2(v[2], v[3]));
  short2 s0, s1;
  __builtin_memcpy(&s0, &h0, sizeof(s0));
  __builtin_memcpy(&s1, &h1, sizeof(s1));
  r[0] = s0.x; r[1] = s0.y; r[2] = s1.x; r[3] = s1.y;
  return r;
}

// ---------------------------------------------------------------------------
// K0: x (fp32->bf16), W (fp32->bf16)
// ---------------------------------------------------------------------------
#define NX (NB * CH * LL)          // 4,194,304
#define NW (OUTC * 3 * CH)         // 24,576
__global__ __launch_bounds__(256)
void cvt_inputs(const float* __restrict__ x, const float* __restrict__ W,
                u16* __restrict__ xb, u16* __restrict__ Wb)
{
  const size_t t8 = ((size_t)blockIdx.x * 256 + threadIdx.x) * 8;
  if (t8 < NX) {
    float v[8];
    *(f32x4*)(v)     = *(const f32x4*)(x + t8);
    *(f32x4*)(v + 4) = *(const f32x4*)(x + t8 + 4);
    *(s16x8*)(xb + t8) = pack8c(v);
  } else if (t8 - NX < NW) {
    const size_t w8 = t8 - NX;
    float v[8];
    *(f32x4*)(v)     = *(const f32x4*)(W + w8);
    *(f32x4*)(v + 4) = *(const f32x4*)(W + w8 + 4);
    *(s16x8*)(Wb + w8) = pack8c(v);
  }
}

// ---------------------------------------------------------------------------
// K1: y1[n] = xb[n] * m[n]  (+ writes mP bf16 B-fragments for K2)
// Quad-buffered gload_lds pipeline, prefetch distance 3; A-fragments
// register-prefetched distance 1 and issued BEFORE the GLOADs so the
// compiler's MFMA wait (vmcnt(16)) never drains the m-tile stream.
// Per-iter issue: [A:4][G:4][St:2]; steady barrier wait = vmcnt(22).
// ---------------------------------------------------------------------------
__global__ __launch_bounds__(256, 2)
void prop1_pack(const u16* __restrict__ xb, const float* __restrict__ m,
                u16* __restrict__ y1, u16* __restrict__ mP)
{
  __shared__ float smem[4][32 * 128];   // 64 KiB quad-buffered 32x128 fp32 tile

  const int n    = blockIdx.x >> 4;
  const int lt   = blockIdx.x & 15;
  const int tid  = threadIdx.x;
  const int wave = tid >> 6;
  const int lane = tid & 63;
  const int l15  = lane & 15;
  const int g4   = lane >> 4;
  const int colb = lt * 128 + wave * 32;

  const float* mn   = m + (size_t)n * LL * LL + lt * 128;
  const float* gsrc = mn + (size_t)(wave * 8 + (lane >> 5)) * LL + (lane & 31) * 4;
  const u16*   ap   = xb + (size_t)n * CH * LL + (size_t)l15 * LL + g4 * 8;
  u16* q0 = mP + (((size_t)n * 64 * LL + colb + l15) * 4 + g4) * 8; // + kb*65536, h*512
  u16* o  = y1 + (size_t)n * CH * LL + colb + l15;

  f32x4 acc[4][2];
#pragma unroll
  for (int f = 0; f < 4; ++f)
#pragma unroll
    for (int h = 0; h < 2; ++h)
#pragma unroll
      for (int r = 0; r < 4; ++r) acc[f][h][r] = 0.f;

  s16x8 aP[4], aQ[4];

#define ALOAD(R, KB)                                                          \
  { const u16* _ap = ap + (KB) * 32;                                          \
    _Pragma("unroll") for (int f = 0; f < 4; ++f)                             \
      R[f] = *(const s16x8*)(_ap + (size_t)(f * 16) * LL); }

#define GLOAD(BI, KB)                                                         \
  { float* _sb = smem[BI];                                                    \
    _Pragma("unroll") for (int i = 0; i < 4; ++i) {                           \
      const float* _g = gsrc + (size_t)((KB) * 32 + i * 2) * LL;              \
      __builtin_amdgcn_global_load_lds(                                       \
        (const __attribute__((address_space(1))) void*)_g,                    \
        (__attribute__((address_space(3))) void*)(_sb + (wave * 4 + i) * 256),\
        16, 0, 0); } }

  // prologue: A(0) FIRST (oldest), then tiles 0,1,2
  ALOAD(aP, 0)
  __builtin_amdgcn_sched_barrier(0);
  GLOAD(0, 0) GLOAD(1, 1) GLOAD(2, 2)
  __builtin_amdgcn_sched_barrier(0);
  asm volatile("s_waitcnt vmcnt(8)" ::: "memory");   // tile 0 landed (G1+G2 = 8 newer)
  __builtin_amdgcn_s_barrier();
  __builtin_amdgcn_sched_barrier(0);

  // one K-step. Issue order: A(kb+1) | G(kb+3) | ds_read/pack/store/MFMA | wait+barrier
#define K1_STEP(KB, CUR, NXT, VN, LAST)                                       \
  {                                                                           \
    if (!(LAST)) {                                                            \
      ALOAD(NXT, ((KB) + 1 < 64 ? (KB) + 1 : 63))                             \
      __builtin_amdgcn_sched_barrier(0);                                      \
      GLOAD(((KB) + 3) & 3, ((KB) + 3 < 64 ? (KB) + 3 : 63))                  \
      __builtin_amdgcn_sched_barrier(0);                                      \
    }                                                                         \
    const float* _t = smem[(KB) & 3] + wave * 32 + l15;                       \
    float _bv0[8], _bv1[8];                                                   \
    _Pragma("unroll") for (int j = 0; j < 8; ++j) {                           \
      _bv0[j] = _t[(g4 * 8 + j) * 128];                                       \
      _bv1[j] = _t[(g4 * 8 + j) * 128 + 16];                                  \
    }                                                                         \
    s16x8 _b0 = pack8c(_bv0), _b1 = pack8c(_bv1);                             \
    u16* _q = q0 + (size_t)(KB) * 65536;                                      \
    *(s16x8*)(_q)       = _b0;                                                \
    *(s16x8*)(_q + 512) = _b1;                                                \
    _Pragma("unroll") for (int f = 0; f < 4; ++f) {                           \
      acc[f][0] = __builtin_amdgcn_mfma_f32_16x16x32_bf16(CUR[f], _b0, acc[f][0], 0, 0, 0); \
      acc[f][1] = __builtin_amdgcn_mfma_f32_16x16x32_bf16(CUR[f], _b1, acc[f][1], 0, 0, 0); \
    }                                                                         \
    if (!(LAST)) {                                                            \
      __builtin_amdgcn_sched_barrier(0);                                      \
      asm volatile("s_waitcnt vmcnt(" VN ")" ::: "memory");                   \
      __builtin_amdgcn_s_barrier();                                           \
      __builtin_amdgcn_sched_barrier(0);                                      \
    }                                                                         \
  }

  K1_STEP(0, aP, aQ, "14", false)   // retire G(1): G2+A1+G3+St0 = 14 newer
  K1_STEP(1, aQ, aP, "20", false)   // retire G(2): 20 newer
#pragma unroll 1
  for (int kb = 2; kb < 62; kb += 2) {
    K1_STEP(kb,     aP, aQ, "22", false)
    K1_STEP(kb + 1, aQ, aP, "22", false)
  }
  K1_STEP(62, aP, aQ, "22", false)
  K1_STEP(63, aQ, aP, "0",  true)

#pragma unroll
  for (int f = 0; f < 4; ++f)
#pragma unroll
    for (int r = 0; r < 4; ++r) {
      const int row = f * 16 + g4 * 4 + r;
      o[(size_t)row * LL]      = f2bf(acc[f][0][r]);
      o[(size_t)row * LL + 16] = f2bf(acc[f][1][r]);
    }
}

// ---------------------------------------------------------------------------
// K2: y2 = y1 * m (from mP) FUSED with projection epilogue:
//     out[n] = Wb * [xb; y1; y2] + b.  y2 never touches HBM (LDS transpose).
// ---------------------------------------------------------------------------
__global__ __launch_bounds__(256, 2)
void prop2_proj(const u16* __restrict__ y1, const u16* __restrict__ mP,
                const u16* __restrict__ xb, const u16* __restrict__ Wb,
                const float* __restrict__ bias, float* __restrict__ out)
{
  __shared__ u16 yT[128 * 72];   // col-major y2 tile: yT[col*72 + row], 18 KiB

  const int n    = blockIdx.x >> 4;
  const int lt   = blockIdx.x & 15;
  const int tid  = threadIdx.x;
  const int wave = tid >> 6;
  const int lane = tid & 63;
  const int l15  = lane & 15;
  const int g4   = lane >> 4;
  const int colb = lt * 128 + wave * 32;

  const u16* mq = mP + (((size_t)n * 64 * LL + colb + l15) * 4 + g4) * 8;
  const u16* ap = y1 + (size_t)n * CH * LL + (size_t)l15 * LL + g4 * 8;

  f32x4 acc[4][2];
#pragma unroll
  for (int f = 0; f < 4; ++f)
#pragma unroll
    for (int h = 0; h < 2; ++h)
#pragma unroll
      for (int r = 0; r < 4; ++r) acc[f][h][r] = 0.f;

  s16x8 bA0, bA1, bB0, bB1, aA[4], aB[4];

#define K2_LOAD(B0, B1, AV, KB)                                              \
  {                                                                          \
    const u16* _mq = mq + (size_t)(KB) * 65536;                              \
    B0 = *(const s16x8*)(_mq);                                               \
    B1 = *(const s16x8*)(_mq + 512);                                         \
    const u16* _ap = ap + (KB) * 32;                                         \
    _Pragma("unroll") for (int f = 0; f < 4; ++f)                            \
      AV[f] = *(const s16x8*)(_ap + (size_t)(f * 16) * LL);                  \
  }

#define K2_COMP(B0, B1, AV)                                                  \
  _Pragma("unroll") for (int f = 0; f < 4; ++f) {                            \
    acc[f][0] = __builtin_amdgcn_mfma_f32_16x16x32_bf16(AV[f], B0, acc[f][0], 0, 0, 0); \
    acc[f][1] = __builtin_amdgcn_mfma_f32_16x16x32_bf16(AV[f], B1, acc[f][1], 0, 0, 0); \
  }

  K2_LOAD(bA0, bA1, aA, 0)
#pragma unroll 1
  for (int kb = 0; kb < 64; kb += 2) {
    K2_LOAD(bB0, bB1, aB, kb + 1)
    K2_COMP(bA0, bA1, aA)
    if (kb + 2 < 64) K2_LOAD(bA0, bA1, aA, kb + 2)
    K2_COMP(bB0, bB1, aB)
  }

  // ---- epilogue: y2 (acc) -> LDS col-major bf16 ----
#pragma unroll
  for (int f = 0; f < 4; ++f)
#pragma unroll
    for (int h = 0; h < 2; ++h) {
      const int c = wave * 32 + l15 + 16 * h;
      *(s16x4*)(&yT[c * 72 + f * 16 + g4 * 4]) = pack4c(acc[f][h]);
    }
  __syncthreads();

  // ---- projection: out = Wb(128x192) * [xb;y1;y2] + b ----
  f32x4 acc2[8][2];
#pragma unroll
  for (int f = 0; f < 8; ++f)
#pragma unroll
    for (int h = 0; h < 2; ++h)
#pragma unroll
      for (int r = 0; r < 4; ++r) acc2[f][h][r] = 0.f;

  const size_t cb = (size_t)n * CH * LL + colb + l15;
  const u16* xp  = xb + cb + (size_t)(g4 * 8) * LL;
  const u16* y1p = y1 + cb + (size_t)(g4 * 8) * LL;
  const u16* wq  = Wb + (size_t)l15 * 192 + g4 * 8;

#pragma unroll
  for (int kc = 0; kc < 6; ++kc) {
    const int k0 = kc * 32;
    s16x8 b0, b1;
    if (kc < 4) {
      const u16* src = (kc < 2) ? (xp + (size_t)k0 * LL)
                                : (y1p + (size_t)(k0 - 64) * LL);
#pragma unroll
      for (int j = 0; j < 8; ++j) {
        b0[j] = (short)src[(size_t)j * LL];
        b1[j] = (short)src[(size_t)j * LL + 16];
      }
    } else {
      const int rb = (kc - 4) * 32 + g4 * 8;
      b0 = *(const s16x8*)(&yT[(wave * 32 + l15) * 72 + rb]);
      b1 = *(const s16x8*)(&yT[(wave * 32 + l15 + 16) * 72 + rb]);
    }
#pragma unroll
    for (int f = 0; f < 8; ++f) {
      s16x8 af = *(const s16x8*)(wq + (size_t)(f * 16) * 192 + k0);
      acc2[f][0] = __builtin_amdgcn_mfma_f32_16x16x32_bf16(af, b0, acc2[f][0], 0, 0, 0);
      acc2[f][1] = __builtin_amdgcn_mfma_f32_16x16x32_bf16(af, b1, acc2[f][1], 0, 0, 0);
    }
  }

  float* op = out + (size_t)n * OUTC * LL + colb + l15;
#pragma unroll
  for (int f = 0; f < 8; ++f)
#pragma unroll
    for (int r = 0; r < 4; ++r) {
      const int row = f * 16 + g4 * 4 + r;
      op[(size_t)row * LL]      = acc2[f][0][r] + bias[row];
      op[(size_t)row * LL + 16] = acc2[f][1][r] + bias[row];
    }
}

extern "C" void kernel_launch(void* const* d_in, const int* in_sizes, int n_in,
                              void* d_out, int out_size, void* d_ws, size_t ws_size,
                              hipStream_t stream)
{
  const float* x = (const float*)d_in[0];
  const float* m = (const float*)d_in[1];
  const float* W = (const float*)d_in[2];
  const float* b = (const float*)d_in[3];
  float* out = (float*)d_out;

  // workspace layout (u16 elems): y1 | xb | Wb | mP
  u16* y1 = (u16*)d_ws;                          //  8 MiB
  u16* xb = y1 + (size_t)NB * CH * LL;           //  8 MiB
  u16* Wb = xb + (size_t)NB * CH * LL;           // 48 KiB
  u16* mP = (u16*)((char*)d_ws + (25u << 20));   // 268 MiB, 1 MiB-aligned

  cvt_inputs<<<dim3(2060), dim3(256), 0, stream>>>(x, W, xb, Wb);
  prop1_pack<<<dim3(NB * 16), dim3(256), 0, stream>>>(xb, m, y1, mP);
  prop2_proj<<<dim3(NB * 16), dim3(256), 0, stream>>>(y1, mP, xb, Wb, b, out);
}